// Round 2
// baseline (795.412 us; speedup 1.0000x reference)
//
#include <hip/hip_runtime.h>
#include <hip/hip_bf16.h>

typedef __attribute__((ext_vector_type(8))) short short8;
typedef __attribute__((ext_vector_type(4))) float f32x4;
typedef __attribute__((ext_vector_type(4))) unsigned short ushort4v;
typedef __attribute__((ext_vector_type(4))) float float4v;
typedef __attribute__((ext_vector_type(2))) unsigned int uint32x2;

#define NB 2
#define NS 4096
#define ND 1024
#define NH 16
#define NHD 64

// 0.125 * log2(e): folds the 1/sqrt(64) score scale AND the exp->exp2
// conversion into the Q projection (exact up to one fp32 rounding).
#define QSCALE 0.18033688011112042f

__device__ __forceinline__ unsigned short f2bf(float x) {
    union { float f; unsigned u; } v; v.f = x;
    unsigned r = v.u + 0x7FFFu + ((v.u >> 16) & 1u);
    return (unsigned short)(r >> 16);
}

// pack 2 f32 -> u32 of 2 bf16 (RNE), dst[15:0]=lo
__device__ __forceinline__ unsigned cvt_pk_bf16(float lo, float hi) {
    unsigned r;
    asm("v_cvt_pk_bf16_f32 %0, %1, %2" : "=v"(r) : "v"(lo), "v"(hi));
    return r;
}

// async global->LDS, 16B per lane. LDS dest = wave-uniform base + lane*16.
__device__ __forceinline__ void gload_lds16(const unsigned short* g, unsigned short* l) {
    __builtin_amdgcn_global_load_lds(
        (const __attribute__((address_space(1))) void*)g,
        (__attribute__((address_space(3))) void*)l,
        16, 0, 0);
}

__global__ void rope_table_kernel(float* __restrict__ cosT, float* __restrict__ sinT) {
    int i = blockIdx.x * blockDim.x + threadIdx.x;  // [0, NS*32)
    int p = i & 31, s = i >> 5;
    float theta = exp2f(-(float)(2 * p) * (13.287712379549449f / 64.0f));  // 10000^(-2p/64)
    float ang = (float)s * theta;
    float sv, cv;
    sincosf(ang, &sv, &cv);
    cosT[i] = cv; sinT[i] = sv;
}

// fp32 -> bf16 elementwise cast, 8 elems/thread (32B read, 16B write).
__global__ void cast_bf16_kernel(const float* __restrict__ in, unsigned short* __restrict__ out, int n8) {
    int i = blockIdx.x * blockDim.x + threadIdx.x;
    if (i >= n8) return;
    float4v a0 = *(const float4v*)(&in[(size_t)i * 8]);
    float4v a1 = *(const float4v*)(&in[(size_t)i * 8 + 4]);
    short8 s8;
    s8[0] = (short)f2bf(a0.x); s8[1] = (short)f2bf(a0.y);
    s8[2] = (short)f2bf(a0.z); s8[3] = (short)f2bf(a0.w);
    s8[4] = (short)f2bf(a1.x); s8[5] = (short)f2bf(a1.y);
    s8[6] = (short)f2bf(a1.z); s8[7] = (short)f2bf(a1.w);
    *(short8*)(&out[(size_t)i * 8]) = s8;
}

// C = A @ W^T + bias. A: [8192][1024] bf16. W: [1024][1024] bf16 row-major.
// m97 structure: 128x128 tile, BK=32, linear LDS (NO padding - required by
// global_load_lds), width-16 global_load_lds staging, ds_read_b128 fragments.
// EPI 0: plain -> out float32 row-major [8192][1024]  (d_out is fp32!)
// EPI 1: RoPE  -> out [B,H,S,HD] bf16, scaled by oscale (Q pre-scaling)
// EPI 2: V^T   -> out [B,H,HD,S] bf16
template<int EPI>
__global__ __launch_bounds__(256, 2) void gemm_kernel(
    const unsigned short* __restrict__ A,
    const unsigned short* __restrict__ Wb,
    const float* __restrict__ bias,
    void* __restrict__ outv,
    const float* __restrict__ cosT,
    const float* __restrict__ sinT,
    float oscale)
{
    __shared__ unsigned short As[128 * 32];  // linear: row stride 32 (64B)
    __shared__ unsigned short Bs[128 * 32];
    const int t = threadIdx.x;
    const int wave = t >> 6, lane = t & 63;
    const int quad = lane >> 4, l15 = lane & 15;
    const int wm = (wave & 1) * 64, wn = (wave >> 1) * 64;
    const int m0 = blockIdx.y * 128, n0 = blockIdx.x * 128;

    f32x4 acc[4][4];
#pragma unroll
    for (int i = 0; i < 4; i++)
#pragma unroll
        for (int j = 0; j < 4; j++)
            acc[i][j] = f32x4{0.f, 0.f, 0.f, 0.f};

    for (int k0 = 0; k0 < ND; k0 += 32) {
#pragma unroll
        for (int p = 0; p < 2; p++) {
            int idx = p * 256 + t;
            int r = idx >> 2, c = (idx & 3) * 8;
            unsigned short* ldsA = &As[(size_t)(p * 256 + wave * 64) * 8];
            unsigned short* ldsB = &Bs[(size_t)(p * 256 + wave * 64) * 8];
            gload_lds16(&A[(size_t)(m0 + r) * ND + k0 + c], ldsA);
            gload_lds16(&Wb[(size_t)(n0 + r) * ND + k0 + c], ldsB);
        }
        __syncthreads();  // compiler emits vmcnt(0) drain here

        short8 af[4], bfr[4];
#pragma unroll
        for (int mt = 0; mt < 4; mt++)
            af[mt] = *(const short8*)(&As[(wm + mt * 16 + l15) * 32 + quad * 8]);
#pragma unroll
        for (int nt = 0; nt < 4; nt++)
            bfr[nt] = *(const short8*)(&Bs[(wn + nt * 16 + l15) * 32 + quad * 8]);
#pragma unroll
        for (int mt = 0; mt < 4; mt++)
#pragma unroll
            for (int nt = 0; nt < 4; nt++) {
                if (EPI == 0)
                    acc[mt][nt] = __builtin_amdgcn_mfma_f32_16x16x32_bf16(bfr[nt], af[mt], acc[mt][nt], 0, 0, 0);
                else
                    acc[mt][nt] = __builtin_amdgcn_mfma_f32_16x16x32_bf16(af[mt], bfr[nt], acc[mt][nt], 0, 0, 0);
            }
        __syncthreads();
    }

    if (EPI == 0) {
        // operands swapped: D[m=W-row -> quad*4+r][n=seq -> l15]; fp32 output
        float* out = (float*)outv;
#pragma unroll
        for (int mt = 0; mt < 4; mt++) {
            int gm = m0 + wm + mt * 16 + l15;  // seq row
#pragma unroll
            for (int nt = 0; nt < 4; nt++) {
                int gn0 = n0 + wn + nt * 16 + quad * 4;  // feature
                float4v fv;
#pragma unroll
                for (int r = 0; r < 4; r++)
                    fv[r] = acc[mt][nt][r] + bias[gn0 + r];
                *(float4v*)(&out[(size_t)gm * ND + gn0]) = fv;
            }
        }
    } else if (EPI == 1) {
        // D[m=seq -> quad*4+r][n=feature -> l15]
        unsigned short* out = (unsigned short*)outv;
#pragma unroll
        for (int nt = 0; nt < 4; nt++) {
            int gn = n0 + wn + nt * 16 + l15;
            int h = gn >> 6, hd = gn & 63, pr = hd >> 1, im = gn & 1;
            float bv = bias[gn];
#pragma unroll
            for (int mt = 0; mt < 4; mt++) {
                int gm0 = m0 + wm + mt * 16 + quad * 4;
#pragma unroll
                for (int r = 0; r < 4; r++) {
                    int gm = gm0 + r;
                    int b = gm >> 12, s = gm & 4095;
                    float v = acc[mt][nt][r] + bv;
                    float pv = __shfl_xor(v, 1, 64);  // partner feature gn^1, same seq
                    float cv = cosT[s * 32 + pr], sv = sinT[s * 32 + pr];
                    float o = im ? (pv * sv + v * cv) : (v * cv - pv * sv);
                    out[((size_t)(b * NH + h) * NS + s) * NHD + hd] = f2bf(o * oscale);
                }
            }
        }
    } else {
        // V^T: out[((b*H+h)*HD+hd)*S + s]
        unsigned short* out = (unsigned short*)outv;
#pragma unroll
        for (int nt = 0; nt < 4; nt++) {
            int gn = n0 + wn + nt * 16 + l15;
            int h = gn >> 6, hd = gn & 63;
            float bv = bias[gn];
#pragma unroll
            for (int mt = 0; mt < 4; mt++) {
                int gm0 = m0 + wm + mt * 16 + quad * 4;
                int b = gm0 >> 12, s0 = gm0 & 4095;
                ushort4v pk;
#pragma unroll
                for (int r = 0; r < 4; r++)
                    pk[r] = f2bf(acc[mt][nt][r] + bv);
                *(ushort4v*)(&out[((size_t)(b * NH + h) * NHD + hd) * NS + s0]) = pk;
            }
        }
    }
}

// Flash attention. Qr: [BH][S][64] bf16, RoPE'd AND pre-scaled by 0.125*log2e.
// Kr: [BH][S][64] bf16 RoPE'd. Vt: [BH][64][S] bf16.
// Yatt: [B*S][1024] bf16. Block: 128 q-rows of one (b,h); wave owns 32 q-rows.
// S^T = K.Q^T (softmax axis in-lane + xor16/32, exp2 domain); O^T += V^T.P^T.
// PV split by nt-half so Pw is 16 rows -> LDS 53248 B -> 3 blocks/CU.
__global__ __launch_bounds__(256, 3) void flash_kernel(
    const unsigned short* __restrict__ Qr,
    const unsigned short* __restrict__ Kr,
    const unsigned short* __restrict__ Vt,
    unsigned short* __restrict__ Yatt)
{
    __shared__ unsigned short Ks[128 * 72];    // pad 64->72
    __shared__ unsigned short Vs[64 * 136];    // pad 128->136
    __shared__ unsigned short Pw[4][16 * 136]; // per-wave P half-tile [qrow16][key128]
    const int t = threadIdx.x;
    const int wave = t >> 6, lane = t & 63;
    const int quad = lane >> 4, l15 = lane & 15;
    const int bh = blockIdx.y;
    const int qb = blockIdx.x * 128;
    const int wq = wave * 32;
    const size_t base = (size_t)bh * NS * NHD;

    short8 qf[2][2];
#pragma unroll
    for (int nt = 0; nt < 2; nt++)
#pragma unroll
        for (int kk = 0; kk < 2; kk++)
            qf[nt][kk] = *(const short8*)(&Qr[base + (size_t)(qb + wq + nt * 16 + l15) * NHD + kk * 32 + quad * 8]);

    f32x4 accO[4][2];
#pragma unroll
    for (int i = 0; i < 4; i++)
#pragma unroll
        for (int j = 0; j < 2; j++)
            accO[i][j] = f32x4{0.f, 0.f, 0.f, 0.f};
    float mrow[2] = {-1e30f, -1e30f};
    float lrow[2] = {0.f, 0.f};

    for (int j0 = 0; j0 < NS; j0 += 128) {
#pragma unroll
        for (int p = 0; p < 4; p++) {
            int idx = p * 256 + t;
            { int r = idx >> 3, c = (idx & 7) * 8;
              *(short8*)(&Ks[r * 72 + c]) = *(const short8*)(&Kr[base + (size_t)(j0 + r) * NHD + c]); }
            { int r = idx >> 4, c = (idx & 15) * 8;
              *(short8*)(&Vs[r * 136 + c]) = *(const short8*)(&Vt[(size_t)(bh * NHD + r) * NS + j0 + c]); }
        }
        __syncthreads();

        // S^T = K . Q^T  (scores arrive already in exp2 domain: Q pre-scaled)
        f32x4 sa[8][2];
#pragma unroll
        for (int mt = 0; mt < 8; mt++)
#pragma unroll
            for (int nt = 0; nt < 2; nt++)
                sa[mt][nt] = f32x4{0.f, 0.f, 0.f, 0.f};
#pragma unroll
        for (int kk = 0; kk < 2; kk++)
#pragma unroll
            for (int mt = 0; mt < 8; mt++) {
                short8 ak = *(const short8*)(&Ks[(mt * 16 + l15) * 72 + kk * 32 + quad * 8]);
#pragma unroll
                for (int nt = 0; nt < 2; nt++)
                    sa[mt][nt] = __builtin_amdgcn_mfma_f32_16x16x32_bf16(ak, qf[nt][kk], sa[mt][nt], 0, 0, 0);
            }

#pragma unroll
        for (int nt = 0; nt < 2; nt++) {
            // --- softmax (exp2 domain), max3-friendly tree ---
            float mm[8];
#pragma unroll
            for (int mt = 0; mt < 8; mt++)
                mm[mt] = fmaxf(fmaxf(sa[mt][nt][0], sa[mt][nt][1]),
                               fmaxf(sa[mt][nt][2], sa[mt][nt][3]));
            float mx = fmaxf(fmaxf(fmaxf(mm[0], mm[1]), fmaxf(mm[2], mm[3])),
                             fmaxf(fmaxf(mm[4], mm[5]), fmaxf(mm[6], mm[7])));
            mx = fmaxf(mx, __shfl_xor(mx, 16, 64));
            mx = fmaxf(mx, __shfl_xor(mx, 32, 64));
            float mnew = fmaxf(mrow[nt], mx);
            float alpha = exp2f(mrow[nt] - mnew);
            float ls0 = 0.f, ls1 = 0.f, ls2 = 0.f, ls3 = 0.f;
#pragma unroll
            for (int mt = 0; mt < 8; mt++) {
                float p0 = exp2f(sa[mt][nt][0] - mnew);
                float p1 = exp2f(sa[mt][nt][1] - mnew);
                float p2 = exp2f(sa[mt][nt][2] - mnew);
                float p3 = exp2f(sa[mt][nt][3] - mnew);
                ls0 += p0; ls1 += p1; ls2 += p2; ls3 += p3;
                uint32x2 pk;
                pk.x = cvt_pk_bf16(p0, p1);
                pk.y = cvt_pk_bf16(p2, p3);
                *(uint32x2*)(&Pw[wave][l15 * 136 + mt * 16 + quad * 4]) = pk;
            }
            float lsum = (ls0 + ls1) + (ls2 + ls3);
            lsum += __shfl_xor(lsum, 16, 64);
            lsum += __shfl_xor(lsum, 32, 64);
            lrow[nt] = lrow[nt] * alpha + lsum;
            mrow[nt] = mnew;
#pragma unroll
            for (int mt2 = 0; mt2 < 4; mt2++)
#pragma unroll
                for (int r = 0; r < 4; r++)
                    accO[mt2][nt][r] *= alpha;

            // --- PV half-tile: O^T[:,nt] += V^T . P^T (Pw write->read same wave,
            //     ordered by lgkmcnt; no barrier needed) ---
#pragma unroll
            for (int kk2 = 0; kk2 < 4; kk2++) {
                short8 av[4];
#pragma unroll
                for (int mt2 = 0; mt2 < 4; mt2++)
                    av[mt2] = *(const short8*)(&Vs[(mt2 * 16 + l15) * 136 + kk2 * 32 + quad * 8]);
                short8 bp = *(const short8*)(&Pw[wave][l15 * 136 + kk2 * 32 + quad * 8]);
#pragma unroll
                for (int mt2 = 0; mt2 < 4; mt2++)
                    accO[mt2][nt] = __builtin_amdgcn_mfma_f32_16x16x32_bf16(av[mt2], bp, accO[mt2][nt], 0, 0, 0);
            }
        }
        __syncthreads();
    }

    int b = bh >> 4, h = bh & 15;
#pragma unroll
    for (int nt = 0; nt < 2; nt++) {
        float rl = 1.f / lrow[nt];
        int s = qb + wq + nt * 16 + l15;
#pragma unroll
        for (int mt2 = 0; mt2 < 4; mt2++) {
            uint32x2 pk;
            pk.x = cvt_pk_bf16(accO[mt2][nt][0] * rl, accO[mt2][nt][1] * rl);
            pk.y = cvt_pk_bf16(accO[mt2][nt][2] * rl, accO[mt2][nt][3] * rl);
            *(uint32x2*)(&Yatt[((size_t)(b * NS + s)) * ND + h * NHD + mt2 * 16 + quad * 4]) = pk;
        }
    }
}

extern "C" void kernel_launch(void* const* d_in, const int* in_sizes, int n_in,
                              void* d_out, int out_size, void* d_ws, size_t ws_size,
                              hipStream_t stream) {
    // dict order (contractual): consulta, chave, valor, Wq, bq, Wk, bk, Wv, bv, Wo, bo
    const float* consulta = (const float*)d_in[0];
    const float* chave    = (const float*)d_in[1];
    const float* valor    = (const float*)d_in[2];
    const float* Wq = (const float*)d_in[3];
    const float* bq = (const float*)d_in[4];
    const float* Wk = (const float*)d_in[5];
    const float* bk = (const float*)d_in[6];
    const float* Wv = (const float*)d_in[7];
    const float* bv = (const float*)d_in[8];
    const float* Wo = (const float*)d_in[9];
    const float* bo = (const float*)d_in[10];

    const size_t NX = (size_t)8192 * 1024;

    float* cosT = (float*)d_ws;
    float* sinT = cosT + (size_t)NS * 32;
    unsigned short* Qrb = (unsigned short*)(sinT + (size_t)NS * 32);
    unsigned short* Krb = Qrb + NX;
    unsigned short* Vtb = Krb + NX;
    unsigned short* Yat = Vtb + NX;
    unsigned short* Abf = Yat + NX;            // bf16 activation staging (reused)
    unsigned short* Wbf = Abf + NX;            // bf16 weight staging (reused)

    rope_table_kernel<<<NS * 32 / 256, 256, 0, stream>>>(cosT, sinT);

    const int ACT8 = (int)(NX / 8);   // 1048576 vec8 chunks
    const int W8 = ND * ND / 8;       // 131072

    dim3 ggrid(8, 64);

    cast_bf16_kernel<<<ACT8 / 256, 256, 0, stream>>>(consulta, Abf, ACT8);
    cast_bf16_kernel<<<W8 / 256, 256, 0, stream>>>(Wq, Wbf, W8);
    gemm_kernel<1><<<ggrid, 256, 0, stream>>>(Abf, Wbf, bq, Qrb, cosT, sinT, QSCALE);

    cast_bf16_kernel<<<ACT8 / 256, 256, 0, stream>>>(chave, Abf, ACT8);
    cast_bf16_kernel<<<W8 / 256, 256, 0, stream>>>(Wk, Wbf, W8);
    gemm_kernel<1><<<ggrid, 256, 0, stream>>>(Abf, Wbf, bk, Krb, cosT, sinT, 1.0f);

    cast_bf16_kernel<<<ACT8 / 256, 256, 0, stream>>>(valor, Abf, ACT8);
    cast_bf16_kernel<<<W8 / 256, 256, 0, stream>>>(Wv, Wbf, W8);
    gemm_kernel<2><<<ggrid, 256, 0, stream>>>(Abf, Wbf, bv, Vtb, cosT, sinT, 1.0f);

    flash_kernel<<<dim3(32, 32), 256, 0, stream>>>(Qrb, Krb, Vtb, Yat);

    // d_out is FLOAT32 (reference output dtype)
    cast_bf16_kernel<<<W8 / 256, 256, 0, stream>>>(Wo, Wbf, W8);
    gemm_kernel<0><<<ggrid, 256, 0, stream>>>(Yat, Wbf, bo, d_out, cosT, sinT, 1.0f);
}

// Round 3
// 587.629 us; speedup vs baseline: 1.3536x; 1.3536x over previous
//
#include <hip/hip_runtime.h>
#include <hip/hip_bf16.h>

typedef __attribute__((ext_vector_type(8))) short short8;
typedef __attribute__((ext_vector_type(4))) float f32x4;
typedef __attribute__((ext_vector_type(4))) unsigned short ushort4v;
typedef __attribute__((ext_vector_type(4))) float float4v;
typedef __attribute__((ext_vector_type(2))) unsigned int uint32x2;

#define NB 2
#define NS 4096
#define ND 1024
#define NH 16
#define NHD 64

// 0.125 * log2(e): folds the 1/sqrt(64) score scale AND the exp->exp2
// conversion into the Q projection (exact up to one fp32 rounding).
#define QSCALE 0.18033688011112042f

__device__ __forceinline__ unsigned short f2bf(float x) {
    union { float f; unsigned u; } v; v.f = x;
    unsigned r = v.u + 0x7FFFu + ((v.u >> 16) & 1u);
    return (unsigned short)(r >> 16);
}

// pack 2 f32 -> u32 of 2 bf16 (RNE), dst[15:0]=lo
__device__ __forceinline__ unsigned cvt_pk_bf16(float lo, float hi) {
    unsigned r;
    asm("v_cvt_pk_bf16_f32 %0, %1, %2" : "=v"(r) : "v"(lo), "v"(hi));
    return r;
}

// async global->LDS, 16B per lane. LDS dest = wave-uniform base + lane*16.
__device__ __forceinline__ void gload_lds16(const unsigned short* g, unsigned short* l) {
    __builtin_amdgcn_global_load_lds(
        (const __attribute__((address_space(1))) void*)g,
        (__attribute__((address_space(3))) void*)l,
        16, 0, 0);
}

__global__ void rope_table_kernel(float* __restrict__ cosT, float* __restrict__ sinT) {
    int i = blockIdx.x * blockDim.x + threadIdx.x;  // [0, NS*32)
    int p = i & 31, s = i >> 5;
    float theta = exp2f(-(float)(2 * p) * (13.287712379549449f / 64.0f));  // 10000^(-2p/64)
    float ang = (float)s * theta;
    float sv, cv;
    sincosf(ang, &sv, &cv);
    cosT[i] = cv; sinT[i] = sv;
}

// fp32 -> bf16 elementwise cast, 8 elems/thread (32B read, 16B write).
__global__ void cast_bf16_kernel(const float* __restrict__ in, unsigned short* __restrict__ out, int n8) {
    int i = blockIdx.x * blockDim.x + threadIdx.x;
    if (i >= n8) return;
    float4v a0 = *(const float4v*)(&in[(size_t)i * 8]);
    float4v a1 = *(const float4v*)(&in[(size_t)i * 8 + 4]);
    short8 s8;
    s8[0] = (short)f2bf(a0.x); s8[1] = (short)f2bf(a0.y);
    s8[2] = (short)f2bf(a0.z); s8[3] = (short)f2bf(a0.w);
    s8[4] = (short)f2bf(a1.x); s8[5] = (short)f2bf(a1.y);
    s8[6] = (short)f2bf(a1.z); s8[7] = (short)f2bf(a1.w);
    *(short8*)(&out[(size_t)i * 8]) = s8;
}

// C = A @ W^T + bias. A: [8192][1024] bf16. W: [1024][1024] bf16 row-major.
// m97 structure: 128x128 tile, BK=32, linear LDS (NO padding - required by
// global_load_lds), width-16 global_load_lds staging, ds_read_b128 fragments.
// EPI 0: plain -> out float32 row-major [8192][1024]  (d_out is fp32!)
// EPI 1: RoPE  -> out [B,H,S,HD] bf16, scaled by oscale (Q pre-scaling)
// EPI 2: V^T   -> out [B,H,HD,S] bf16
template<int EPI>
__global__ __launch_bounds__(256, 2) void gemm_kernel(
    const unsigned short* __restrict__ A,
    const unsigned short* __restrict__ Wb,
    const float* __restrict__ bias,
    void* __restrict__ outv,
    const float* __restrict__ cosT,
    const float* __restrict__ sinT,
    float oscale)
{
    __shared__ unsigned short As[128 * 32];  // linear: row stride 32 (64B)
    __shared__ unsigned short Bs[128 * 32];
    const int t = threadIdx.x;
    const int wave = t >> 6, lane = t & 63;
    const int quad = lane >> 4, l15 = lane & 15;
    const int wm = (wave & 1) * 64, wn = (wave >> 1) * 64;
    const int m0 = blockIdx.y * 128, n0 = blockIdx.x * 128;

    f32x4 acc[4][4];
#pragma unroll
    for (int i = 0; i < 4; i++)
#pragma unroll
        for (int j = 0; j < 4; j++)
            acc[i][j] = f32x4{0.f, 0.f, 0.f, 0.f};

    for (int k0 = 0; k0 < ND; k0 += 32) {
#pragma unroll
        for (int p = 0; p < 2; p++) {
            int idx = p * 256 + t;
            int r = idx >> 2, c = (idx & 3) * 8;
            unsigned short* ldsA = &As[(size_t)(p * 256 + wave * 64) * 8];
            unsigned short* ldsB = &Bs[(size_t)(p * 256 + wave * 64) * 8];
            gload_lds16(&A[(size_t)(m0 + r) * ND + k0 + c], ldsA);
            gload_lds16(&Wb[(size_t)(n0 + r) * ND + k0 + c], ldsB);
        }
        __syncthreads();  // compiler emits vmcnt(0) drain here

        short8 af[4], bfr[4];
#pragma unroll
        for (int mt = 0; mt < 4; mt++)
            af[mt] = *(const short8*)(&As[(wm + mt * 16 + l15) * 32 + quad * 8]);
#pragma unroll
        for (int nt = 0; nt < 4; nt++)
            bfr[nt] = *(const short8*)(&Bs[(wn + nt * 16 + l15) * 32 + quad * 8]);
#pragma unroll
        for (int mt = 0; mt < 4; mt++)
#pragma unroll
            for (int nt = 0; nt < 4; nt++) {
                if (EPI == 0)
                    acc[mt][nt] = __builtin_amdgcn_mfma_f32_16x16x32_bf16(bfr[nt], af[mt], acc[mt][nt], 0, 0, 0);
                else
                    acc[mt][nt] = __builtin_amdgcn_mfma_f32_16x16x32_bf16(af[mt], bfr[nt], acc[mt][nt], 0, 0, 0);
            }
        __syncthreads();
    }

    if (EPI == 0) {
        // operands swapped: D[m=W-row -> quad*4+r][n=seq -> l15]; fp32 output
        float* out = (float*)outv;
#pragma unroll
        for (int mt = 0; mt < 4; mt++) {
            int gm = m0 + wm + mt * 16 + l15;  // seq row
#pragma unroll
            for (int nt = 0; nt < 4; nt++) {
                int gn0 = n0 + wn + nt * 16 + quad * 4;  // feature
                float4v fv;
#pragma unroll
                for (int r = 0; r < 4; r++)
                    fv[r] = acc[mt][nt][r] + bias[gn0 + r];
                *(float4v*)(&out[(size_t)gm * ND + gn0]) = fv;
            }
        }
    } else if (EPI == 1) {
        // D[m=seq -> quad*4+r][n=feature -> l15]
        unsigned short* out = (unsigned short*)outv;
#pragma unroll
        for (int nt = 0; nt < 4; nt++) {
            int gn = n0 + wn + nt * 16 + l15;
            int h = gn >> 6, hd = gn & 63, pr = hd >> 1, im = gn & 1;
            float bv = bias[gn];
#pragma unroll
            for (int mt = 0; mt < 4; mt++) {
                int gm0 = m0 + wm + mt * 16 + quad * 4;
#pragma unroll
                for (int r = 0; r < 4; r++) {
                    int gm = gm0 + r;
                    int b = gm >> 12, s = gm & 4095;
                    float v = acc[mt][nt][r] + bv;
                    float pv = __shfl_xor(v, 1, 64);  // partner feature gn^1, same seq
                    float cv = cosT[s * 32 + pr], sv = sinT[s * 32 + pr];
                    float o = im ? (pv * sv + v * cv) : (v * cv - pv * sv);
                    out[((size_t)(b * NH + h) * NS + s) * NHD + hd] = f2bf(o * oscale);
                }
            }
        }
    } else {
        // V^T: out[((b*H+h)*HD+hd)*S + s]
        unsigned short* out = (unsigned short*)outv;
#pragma unroll
        for (int nt = 0; nt < 4; nt++) {
            int gn = n0 + wn + nt * 16 + l15;
            int h = gn >> 6, hd = gn & 63;
            float bv = bias[gn];
#pragma unroll
            for (int mt = 0; mt < 4; mt++) {
                int gm0 = m0 + wm + mt * 16 + quad * 4;
                int b = gm0 >> 12, s0 = gm0 & 4095;
                ushort4v pk;
#pragma unroll
                for (int r = 0; r < 4; r++)
                    pk[r] = f2bf(acc[mt][nt][r] + bv);
                *(ushort4v*)(&out[((size_t)(b * NH + h) * NHD + hd) * NS + s0]) = pk;
            }
        }
    }
}

// Flash attention. Qr: [BH][S][64] bf16, RoPE'd AND pre-scaled by 0.125*log2e.
// Kr: [BH][S][64] bf16 RoPE'd. Vt: [BH][64][S] bf16.
// Yatt: [B*S][1024] bf16. Block: 128 q-rows of one (b,h); wave owns 32 q-rows.
// S^T = K.Q^T (softmax axis in-lane + xor16/32, exp2 domain); O^T += V^T.P^T.
// PV split by nt-half: Pw 16 rows -> LDS 53248 B -> 3 blocks/CU by LDS.
// launch_bounds min-waves=2 ONLY (NOT 3: forcing 3 caused 84-VGPR spill hell,
// 502 MB scratch writes, round-2 regression). Natural alloc ~130-160 VGPR
// still permits 3 waves/SIMD (<=170).
__global__ __launch_bounds__(256, 2) void flash_kernel(
    const unsigned short* __restrict__ Qr,
    const unsigned short* __restrict__ Kr,
    const unsigned short* __restrict__ Vt,
    unsigned short* __restrict__ Yatt)
{
    __shared__ unsigned short Ks[128 * 72];    // pad 64->72
    __shared__ unsigned short Vs[64 * 136];    // pad 128->136
    __shared__ unsigned short Pw[4][16 * 136]; // per-wave P half-tile [qrow16][key128]
    const int t = threadIdx.x;
    const int wave = t >> 6, lane = t & 63;
    const int quad = lane >> 4, l15 = lane & 15;
    const int bh = blockIdx.y;
    const int qb = blockIdx.x * 128;
    const int wq = wave * 32;
    const size_t base = (size_t)bh * NS * NHD;

    short8 qf[2][2];
#pragma unroll
    for (int nt = 0; nt < 2; nt++)
#pragma unroll
        for (int kk = 0; kk < 2; kk++)
            qf[nt][kk] = *(const short8*)(&Qr[base + (size_t)(qb + wq + nt * 16 + l15) * NHD + kk * 32 + quad * 8]);

    f32x4 accO[4][2];
#pragma unroll
    for (int i = 0; i < 4; i++)
#pragma unroll
        for (int j = 0; j < 2; j++)
            accO[i][j] = f32x4{0.f, 0.f, 0.f, 0.f};
    float mrow[2] = {-1e30f, -1e30f};
    float lrow[2] = {0.f, 0.f};

    for (int j0 = 0; j0 < NS; j0 += 128) {
#pragma unroll
        for (int p = 0; p < 4; p++) {
            int idx = p * 256 + t;
            { int r = idx >> 3, c = (idx & 7) * 8;
              *(short8*)(&Ks[r * 72 + c]) = *(const short8*)(&Kr[base + (size_t)(j0 + r) * NHD + c]); }
            { int r = idx >> 4, c = (idx & 15) * 8;
              *(short8*)(&Vs[r * 136 + c]) = *(const short8*)(&Vt[(size_t)(bh * NHD + r) * NS + j0 + c]); }
        }
        __syncthreads();

        // S^T = K . Q^T  (scores arrive already in exp2 domain: Q pre-scaled)
        f32x4 sa[8][2];
#pragma unroll
        for (int mt = 0; mt < 8; mt++)
#pragma unroll
            for (int nt = 0; nt < 2; nt++)
                sa[mt][nt] = f32x4{0.f, 0.f, 0.f, 0.f};
#pragma unroll
        for (int kk = 0; kk < 2; kk++)
#pragma unroll
            for (int mt = 0; mt < 8; mt++) {
                short8 ak = *(const short8*)(&Ks[(mt * 16 + l15) * 72 + kk * 32 + quad * 8]);
#pragma unroll
                for (int nt = 0; nt < 2; nt++)
                    sa[mt][nt] = __builtin_amdgcn_mfma_f32_16x16x32_bf16(ak, qf[nt][kk], sa[mt][nt], 0, 0, 0);
            }

#pragma unroll
        for (int nt = 0; nt < 2; nt++) {
            // --- softmax (exp2 domain), max3-friendly tree ---
            float mm[8];
#pragma unroll
            for (int mt = 0; mt < 8; mt++)
                mm[mt] = fmaxf(fmaxf(sa[mt][nt][0], sa[mt][nt][1]),
                               fmaxf(sa[mt][nt][2], sa[mt][nt][3]));
            float mx = fmaxf(fmaxf(fmaxf(mm[0], mm[1]), fmaxf(mm[2], mm[3])),
                             fmaxf(fmaxf(mm[4], mm[5]), fmaxf(mm[6], mm[7])));
            mx = fmaxf(mx, __shfl_xor(mx, 16, 64));
            mx = fmaxf(mx, __shfl_xor(mx, 32, 64));
            float mnew = fmaxf(mrow[nt], mx);
            float alpha = exp2f(mrow[nt] - mnew);
            float ls0 = 0.f, ls1 = 0.f, ls2 = 0.f, ls3 = 0.f;
#pragma unroll
            for (int mt = 0; mt < 8; mt++) {
                float p0 = exp2f(sa[mt][nt][0] - mnew);
                float p1 = exp2f(sa[mt][nt][1] - mnew);
                float p2 = exp2f(sa[mt][nt][2] - mnew);
                float p3 = exp2f(sa[mt][nt][3] - mnew);
                ls0 += p0; ls1 += p1; ls2 += p2; ls3 += p3;
                uint32x2 pk;
                pk.x = cvt_pk_bf16(p0, p1);
                pk.y = cvt_pk_bf16(p2, p3);
                *(uint32x2*)(&Pw[wave][l15 * 136 + mt * 16 + quad * 4]) = pk;
            }
            float lsum = (ls0 + ls1) + (ls2 + ls3);
            lsum += __shfl_xor(lsum, 16, 64);
            lsum += __shfl_xor(lsum, 32, 64);
            lrow[nt] = lrow[nt] * alpha + lsum;
            mrow[nt] = mnew;
#pragma unroll
            for (int mt2 = 0; mt2 < 4; mt2++)
#pragma unroll
                for (int r = 0; r < 4; r++)
                    accO[mt2][nt][r] *= alpha;

            // --- PV half-tile: O^T[:,nt] += V^T . P^T (Pw write->read same wave,
            //     ordered by lgkmcnt; no barrier needed) ---
#pragma unroll
            for (int kk2 = 0; kk2 < 4; kk2++) {
                short8 av[4];
#pragma unroll
                for (int mt2 = 0; mt2 < 4; mt2++)
                    av[mt2] = *(const short8*)(&Vs[(mt2 * 16 + l15) * 136 + kk2 * 32 + quad * 8]);
                short8 bp = *(const short8*)(&Pw[wave][l15 * 136 + kk2 * 32 + quad * 8]);
#pragma unroll
                for (int mt2 = 0; mt2 < 4; mt2++)
                    accO[mt2][nt] = __builtin_amdgcn_mfma_f32_16x16x32_bf16(av[mt2], bp, accO[mt2][nt], 0, 0, 0);
            }
        }
        __syncthreads();
    }

    int b = bh >> 4, h = bh & 15;
#pragma unroll
    for (int nt = 0; nt < 2; nt++) {
        float rl = 1.f / lrow[nt];
        int s = qb + wq + nt * 16 + l15;
#pragma unroll
        for (int mt2 = 0; mt2 < 4; mt2++) {
            uint32x2 pk;
            pk.x = cvt_pk_bf16(accO[mt2][nt][0] * rl, accO[mt2][nt][1] * rl);
            pk.y = cvt_pk_bf16(accO[mt2][nt][2] * rl, accO[mt2][nt][3] * rl);
            *(uint32x2*)(&Yatt[((size_t)(b * NS + s)) * ND + h * NHD + mt2 * 16 + quad * 4]) = pk;
        }
    }
}

extern "C" void kernel_launch(void* const* d_in, const int* in_sizes, int n_in,
                              void* d_out, int out_size, void* d_ws, size_t ws_size,
                              hipStream_t stream) {
    // dict order (contractual): consulta, chave, valor, Wq, bq, Wk, bk, Wv, bv, Wo, bo
    const float* consulta = (const float*)d_in[0];
    const float* chave    = (const float*)d_in[1];
    const float* valor    = (const float*)d_in[2];
    const float* Wq = (const float*)d_in[3];
    const float* bq = (const float*)d_in[4];
    const float* Wk = (const float*)d_in[5];
    const float* bk = (const float*)d_in[6];
    const float* Wv = (const float*)d_in[7];
    const float* bv = (const float*)d_in[8];
    const float* Wo = (const float*)d_in[9];
    const float* bo = (const float*)d_in[10];

    const size_t NX = (size_t)8192 * 1024;

    float* cosT = (float*)d_ws;
    float* sinT = cosT + (size_t)NS * 32;
    unsigned short* Qrb = (unsigned short*)(sinT + (size_t)NS * 32);
    unsigned short* Krb = Qrb + NX;
    unsigned short* Vtb = Krb + NX;
    unsigned short* Yat = Vtb + NX;
    unsigned short* Abf = Yat + NX;            // bf16 activation staging (reused)
    unsigned short* Wbf = Abf + NX;            // bf16 weight staging (reused)

    rope_table_kernel<<<NS * 32 / 256, 256, 0, stream>>>(cosT, sinT);

    const int ACT8 = (int)(NX / 8);   // 1048576 vec8 chunks
    const int W8 = ND * ND / 8;       // 131072

    dim3 ggrid(8, 64);

    cast_bf16_kernel<<<ACT8 / 256, 256, 0, stream>>>(consulta, Abf, ACT8);
    cast_bf16_kernel<<<W8 / 256, 256, 0, stream>>>(Wq, Wbf, W8);
    gemm_kernel<1><<<ggrid, 256, 0, stream>>>(Abf, Wbf, bq, Qrb, cosT, sinT, QSCALE);

    cast_bf16_kernel<<<ACT8 / 256, 256, 0, stream>>>(chave, Abf, ACT8);
    cast_bf16_kernel<<<W8 / 256, 256, 0, stream>>>(Wk, Wbf, W8);
    gemm_kernel<1><<<ggrid, 256, 0, stream>>>(Abf, Wbf, bk, Krb, cosT, sinT, 1.0f);

    cast_bf16_kernel<<<ACT8 / 256, 256, 0, stream>>>(valor, Abf, ACT8);
    cast_bf16_kernel<<<W8 / 256, 256, 0, stream>>>(Wv, Wbf, W8);
    gemm_kernel<2><<<ggrid, 256, 0, stream>>>(Abf, Wbf, bv, Vtb, cosT, sinT, 1.0f);

    flash_kernel<<<dim3(32, 32), 256, 0, stream>>>(Qrb, Krb, Vtb, Yat);

    // d_out is FLOAT32 (reference output dtype)
    cast_bf16_kernel<<<W8 / 256, 256, 0, stream>>>(Wo, Wbf, W8);
    gemm_kernel<0><<<ggrid, 256, 0, stream>>>(Yat, Wbf, bo, d_out, cosT, sinT, 1.0f);
}

// Round 4
// 560.099 us; speedup vs baseline: 1.4201x; 1.0492x over previous
//
#include <hip/hip_runtime.h>
#include <hip/hip_bf16.h>

typedef __attribute__((ext_vector_type(8))) short short8;
typedef __attribute__((ext_vector_type(4))) float f32x4;
typedef __attribute__((ext_vector_type(4))) unsigned short ushort4v;
typedef __attribute__((ext_vector_type(4))) float float4v;
typedef __attribute__((ext_vector_type(2))) unsigned int uint32x2;

#define NB 2
#define NS 4096
#define ND 1024
#define NH 16
#define NHD 64

// 0.125 * log2(e): folds the 1/sqrt(64) score scale AND the exp->exp2
// conversion into the Q projection (exact up to one fp32 rounding).
#define QSCALE 0.18033688011112042f

__device__ __forceinline__ unsigned short f2bf(float x) {
    union { float f; unsigned u; } v; v.f = x;
    unsigned r = v.u + 0x7FFFu + ((v.u >> 16) & 1u);
    return (unsigned short)(r >> 16);
}

// pack 2 f32 -> u32 of 2 bf16 (RNE), dst[15:0]=lo
__device__ __forceinline__ unsigned cvt_pk_bf16(float lo, float hi) {
    unsigned r;
    asm("v_cvt_pk_bf16_f32 %0, %1, %2" : "=v"(r) : "v"(lo), "v"(hi));
    return r;
}

// async global->LDS, 16B per lane. LDS dest = wave-uniform base + lane*16.
__device__ __forceinline__ void gload_lds16(const unsigned short* g, unsigned short* l) {
    __builtin_amdgcn_global_load_lds(
        (const __attribute__((address_space(1))) void*)g,
        (__attribute__((address_space(3))) void*)l,
        16, 0, 0);
}

__global__ void rope_table_kernel(float* __restrict__ cosT, float* __restrict__ sinT) {
    int i = blockIdx.x * blockDim.x + threadIdx.x;  // [0, NS*32)
    int p = i & 31, s = i >> 5;
    float theta = exp2f(-(float)(2 * p) * (13.287712379549449f / 64.0f));  // 10000^(-2p/64)
    float ang = (float)s * theta;
    float sv, cv;
    sincosf(ang, &sv, &cv);
    cosT[i] = cv; sinT[i] = sv;
}

// fp32 -> bf16 elementwise cast, 8 elems/thread (32B read, 16B write).
__global__ void cast_bf16_kernel(const float* __restrict__ in, unsigned short* __restrict__ out, int n8) {
    int i = blockIdx.x * blockDim.x + threadIdx.x;
    if (i >= n8) return;
    float4v a0 = *(const float4v*)(&in[(size_t)i * 8]);
    float4v a1 = *(const float4v*)(&in[(size_t)i * 8 + 4]);
    short8 s8;
    s8[0] = (short)f2bf(a0.x); s8[1] = (short)f2bf(a0.y);
    s8[2] = (short)f2bf(a0.z); s8[3] = (short)f2bf(a0.w);
    s8[4] = (short)f2bf(a1.x); s8[5] = (short)f2bf(a1.y);
    s8[6] = (short)f2bf(a1.z); s8[7] = (short)f2bf(a1.w);
    *(short8*)(&out[(size_t)i * 8]) = s8;
}

// C = A @ W^T + bias. A: [8192][1024] bf16. W: [1024][1024] bf16 row-major.
// m97 structure: 128x128 tile, BK=32, linear LDS (NO padding - required by
// global_load_lds), width-16 global_load_lds staging, ds_read_b128 fragments.
// EPI 0: plain -> out float32 row-major [8192][1024]  (d_out is fp32!)
// EPI 1: RoPE  -> out [B,H,S,HD] bf16, scaled by oscale (Q pre-scaling)
// EPI 2: V^T   -> out [B,H,HD,S] bf16
template<int EPI>
__global__ __launch_bounds__(256, 2) void gemm_kernel(
    const unsigned short* __restrict__ A,
    const unsigned short* __restrict__ Wb,
    const float* __restrict__ bias,
    void* __restrict__ outv,
    const float* __restrict__ cosT,
    const float* __restrict__ sinT,
    float oscale)
{
    __shared__ unsigned short As[128 * 32];  // linear: row stride 32 (64B)
    __shared__ unsigned short Bs[128 * 32];
    const int t = threadIdx.x;
    const int wave = t >> 6, lane = t & 63;
    const int quad = lane >> 4, l15 = lane & 15;
    const int wm = (wave & 1) * 64, wn = (wave >> 1) * 64;
    const int m0 = blockIdx.y * 128, n0 = blockIdx.x * 128;

    f32x4 acc[4][4];
#pragma unroll
    for (int i = 0; i < 4; i++)
#pragma unroll
        for (int j = 0; j < 4; j++)
            acc[i][j] = f32x4{0.f, 0.f, 0.f, 0.f};

    for (int k0 = 0; k0 < ND; k0 += 32) {
#pragma unroll
        for (int p = 0; p < 2; p++) {
            int idx = p * 256 + t;
            int r = idx >> 2, c = (idx & 3) * 8;
            unsigned short* ldsA = &As[(size_t)(p * 256 + wave * 64) * 8];
            unsigned short* ldsB = &Bs[(size_t)(p * 256 + wave * 64) * 8];
            gload_lds16(&A[(size_t)(m0 + r) * ND + k0 + c], ldsA);
            gload_lds16(&Wb[(size_t)(n0 + r) * ND + k0 + c], ldsB);
        }
        __syncthreads();  // compiler emits vmcnt(0) drain here

        short8 af[4], bfr[4];
#pragma unroll
        for (int mt = 0; mt < 4; mt++)
            af[mt] = *(const short8*)(&As[(wm + mt * 16 + l15) * 32 + quad * 8]);
#pragma unroll
        for (int nt = 0; nt < 4; nt++)
            bfr[nt] = *(const short8*)(&Bs[(wn + nt * 16 + l15) * 32 + quad * 8]);
#pragma unroll
        for (int mt = 0; mt < 4; mt++)
#pragma unroll
            for (int nt = 0; nt < 4; nt++) {
                if (EPI == 0)
                    acc[mt][nt] = __builtin_amdgcn_mfma_f32_16x16x32_bf16(bfr[nt], af[mt], acc[mt][nt], 0, 0, 0);
                else
                    acc[mt][nt] = __builtin_amdgcn_mfma_f32_16x16x32_bf16(af[mt], bfr[nt], acc[mt][nt], 0, 0, 0);
            }
        __syncthreads();
    }

    if (EPI == 0) {
        // operands swapped: D[m=W-row -> quad*4+r][n=seq -> l15]; fp32 output
        float* out = (float*)outv;
#pragma unroll
        for (int mt = 0; mt < 4; mt++) {
            int gm = m0 + wm + mt * 16 + l15;  // seq row
#pragma unroll
            for (int nt = 0; nt < 4; nt++) {
                int gn0 = n0 + wn + nt * 16 + quad * 4;  // feature
                float4v fv;
#pragma unroll
                for (int r = 0; r < 4; r++)
                    fv[r] = acc[mt][nt][r] + bias[gn0 + r];
                *(float4v*)(&out[(size_t)gm * ND + gn0]) = fv;
            }
        }
    } else if (EPI == 1) {
        // D[m=seq -> quad*4+r][n=feature -> l15]
        unsigned short* out = (unsigned short*)outv;
#pragma unroll
        for (int nt = 0; nt < 4; nt++) {
            int gn = n0 + wn + nt * 16 + l15;
            int h = gn >> 6, hd = gn & 63, pr = hd >> 1, im = gn & 1;
            float bv = bias[gn];
#pragma unroll
            for (int mt = 0; mt < 4; mt++) {
                int gm0 = m0 + wm + mt * 16 + quad * 4;
#pragma unroll
                for (int r = 0; r < 4; r++) {
                    int gm = gm0 + r;
                    int b = gm >> 12, s = gm & 4095;
                    float v = acc[mt][nt][r] + bv;
                    float pv = __shfl_xor(v, 1, 64);  // partner feature gn^1, same seq
                    float cv = cosT[s * 32 + pr], sv = sinT[s * 32 + pr];
                    float o = im ? (pv * sv + v * cv) : (v * cv - pv * sv);
                    out[((size_t)(b * NH + h) * NS + s) * NHD + hd] = f2bf(o * oscale);
                }
            }
        }
    } else {
        // V^T: out[((b*H+h)*HD+hd)*S + s]
        unsigned short* out = (unsigned short*)outv;
#pragma unroll
        for (int nt = 0; nt < 4; nt++) {
            int gn = n0 + wn + nt * 16 + l15;
            int h = gn >> 6, hd = gn & 63;
            float bv = bias[gn];
#pragma unroll
            for (int mt = 0; mt < 4; mt++) {
                int gm0 = m0 + wm + mt * 16 + quad * 4;
                int b = gm0 >> 12, s0 = gm0 & 4095;
                ushort4v pk;
#pragma unroll
                for (int r = 0; r < 4; r++)
                    pk[r] = f2bf(acc[mt][nt][r] + bv);
                *(ushort4v*)(&out[((size_t)(b * NH + h) * NHD + hd) * NS + s0]) = pk;
            }
        }
    }
}

// Flash attention. Qr: [BH][S][64] bf16, RoPE'd AND pre-scaled by 0.125*log2e.
// Kr: [BH][S][64] bf16 RoPE'd. Vt: [BH][64][S] bf16.
// Yatt: [B*S][1024] bf16. Block: 128 q-rows of one (b,h); wave owns 32 q-rows.
// S^T = K.Q^T (softmax axis in-lane + xor16/32, exp2 domain); O^T += V^T.P^T.
// Structure (round-4): single-phase PV (av reused across nt), full 32-row Pw;
// T14 async-stage (next tile -> regs at loop top, ds_write after post-PV
// barrier); T13 defer-max (THR=8); T5 setprio around MFMA clusters.
// launch_bounds min-waves=2 ONLY (3 forced an 84-VGPR spill storm in round 2).
__global__ __launch_bounds__(256, 2) void flash_kernel(
    const unsigned short* __restrict__ Qr,
    const unsigned short* __restrict__ Kr,
    const unsigned short* __restrict__ Vt,
    unsigned short* __restrict__ Yatt)
{
    __shared__ unsigned short Ks[128 * 72];    // pad 64->72
    __shared__ unsigned short Vs[64 * 136];    // pad 128->136
    __shared__ unsigned short Pw[4][32 * 136]; // per-wave P [qrow32][key128]
    const int t = threadIdx.x;
    const int wave = t >> 6, lane = t & 63;
    const int quad = lane >> 4, l15 = lane & 15;
    const int bh = blockIdx.y;
    const int qb = blockIdx.x * 128;
    const int wq = wave * 32;
    const size_t base = (size_t)bh * NS * NHD;

    short8 qf[2][2];
#pragma unroll
    for (int nt = 0; nt < 2; nt++)
#pragma unroll
        for (int kk = 0; kk < 2; kk++)
            qf[nt][kk] = *(const short8*)(&Qr[base + (size_t)(qb + wq + nt * 16 + l15) * NHD + kk * 32 + quad * 8]);

    f32x4 accO[4][2];
#pragma unroll
    for (int i = 0; i < 4; i++)
#pragma unroll
        for (int j = 0; j < 2; j++)
            accO[i][j] = f32x4{0.f, 0.f, 0.f, 0.f};
    float mrow[2] = {-1e30f, -1e30f};
    float lrow[2] = {0.f, 0.f};

    // prologue: stage tile 0 directly
#pragma unroll
    for (int p = 0; p < 4; p++) {
        int idx = p * 256 + t;
        { int r = idx >> 3, c = (idx & 7) * 8;
          *(short8*)(&Ks[r * 72 + c]) = *(const short8*)(&Kr[base + (size_t)r * NHD + c]); }
        { int r = idx >> 4, c = (idx & 15) * 8;
          *(short8*)(&Vs[r * 136 + c]) = *(const short8*)(&Vt[(size_t)(bh * NHD + r) * NS + c]); }
    }
    __syncthreads();

    for (int j0 = 0; j0 < NS; j0 += 128) {
        const bool more = (j0 + 128) < NS;

        // T14: issue next tile's global loads NOW; they complete under
        // QK^T + softmax + PV, ds_write happens after the post-PV barrier.
        short8 kpr0, kpr1, kpr2, kpr3, vpr0, vpr1, vpr2, vpr3;
        if (more) {
            int j1 = j0 + 128;
#pragma unroll
            for (int p = 0; p < 4; p++) {
                int idx = p * 256 + t;
                int rk = idx >> 3, ck = (idx & 7) * 8;
                int rv = idx >> 4, cv = (idx & 15) * 8;
                short8 kv = *(const short8*)(&Kr[base + (size_t)(j1 + rk) * NHD + ck]);
                short8 vv = *(const short8*)(&Vt[(size_t)(bh * NHD + rv) * NS + j1 + cv]);
                if (p == 0) { kpr0 = kv; vpr0 = vv; }
                else if (p == 1) { kpr1 = kv; vpr1 = vv; }
                else if (p == 2) { kpr2 = kv; vpr2 = vv; }
                else { kpr3 = kv; vpr3 = vv; }
            }
        }

        // S^T = K . Q^T  (scores arrive already in exp2 domain: Q pre-scaled)
        f32x4 sa[8][2];
#pragma unroll
        for (int mt = 0; mt < 8; mt++)
#pragma unroll
            for (int nt = 0; nt < 2; nt++)
                sa[mt][nt] = f32x4{0.f, 0.f, 0.f, 0.f};
        __builtin_amdgcn_s_setprio(1);
#pragma unroll
        for (int kk = 0; kk < 2; kk++)
#pragma unroll
            for (int mt = 0; mt < 8; mt++) {
                short8 ak = *(const short8*)(&Ks[(mt * 16 + l15) * 72 + kk * 32 + quad * 8]);
#pragma unroll
                for (int nt = 0; nt < 2; nt++)
                    sa[mt][nt] = __builtin_amdgcn_mfma_f32_16x16x32_bf16(ak, qf[nt][kk], sa[mt][nt], 0, 0, 0);
            }
        __builtin_amdgcn_s_setprio(0);

#pragma unroll
        for (int nt = 0; nt < 2; nt++) {
            // --- softmax (exp2 domain), tree max ---
            float mm[8];
#pragma unroll
            for (int mt = 0; mt < 8; mt++)
                mm[mt] = fmaxf(fmaxf(sa[mt][nt][0], sa[mt][nt][1]),
                               fmaxf(sa[mt][nt][2], sa[mt][nt][3]));
            float mx = fmaxf(fmaxf(fmaxf(mm[0], mm[1]), fmaxf(mm[2], mm[3])),
                             fmaxf(fmaxf(mm[4], mm[5]), fmaxf(mm[6], mm[7])));
            mx = fmaxf(mx, __shfl_xor(mx, 16, 64));
            mx = fmaxf(mx, __shfl_xor(mx, 32, 64));
            // T13 defer-max: only rescale when the tile max exceeds the
            // running max by >8 (exp2 domain -> P bounded by 2^8, bf16-safe).
            if (!__all(mx <= mrow[nt] + 8.0f)) {
                float mnew = fmaxf(mrow[nt], mx);
                float alpha = exp2f(mrow[nt] - mnew);
                lrow[nt] *= alpha;
#pragma unroll
                for (int mt2 = 0; mt2 < 4; mt2++)
#pragma unroll
                    for (int r = 0; r < 4; r++)
                        accO[mt2][nt][r] *= alpha;
                mrow[nt] = mnew;
            }
            float mcur = mrow[nt];
            float ls0 = 0.f, ls1 = 0.f, ls2 = 0.f, ls3 = 0.f;
#pragma unroll
            for (int mt = 0; mt < 8; mt++) {
                float p0 = exp2f(sa[mt][nt][0] - mcur);
                float p1 = exp2f(sa[mt][nt][1] - mcur);
                float p2 = exp2f(sa[mt][nt][2] - mcur);
                float p3 = exp2f(sa[mt][nt][3] - mcur);
                ls0 += p0; ls1 += p1; ls2 += p2; ls3 += p3;
                uint32x2 pk;
                pk.x = cvt_pk_bf16(p0, p1);
                pk.y = cvt_pk_bf16(p2, p3);
                *(uint32x2*)(&Pw[wave][(nt * 16 + l15) * 136 + mt * 16 + quad * 4]) = pk;
            }
            float lsum = (ls0 + ls1) + (ls2 + ls3);
            lsum += __shfl_xor(lsum, 16, 64);
            lsum += __shfl_xor(lsum, 32, 64);
            lrow[nt] += lsum;
        }

        // --- PV: O^T += V^T . P^T (av loaded once, reused for both nt;
        //     Pw write->read same wave, ordered by lgkmcnt) ---
        __builtin_amdgcn_s_setprio(1);
#pragma unroll
        for (int kk2 = 0; kk2 < 4; kk2++) {
            short8 av[4], bp[2];
#pragma unroll
            for (int mt2 = 0; mt2 < 4; mt2++)
                av[mt2] = *(const short8*)(&Vs[(mt2 * 16 + l15) * 136 + kk2 * 32 + quad * 8]);
#pragma unroll
            for (int nt = 0; nt < 2; nt++)
                bp[nt] = *(const short8*)(&Pw[wave][(nt * 16 + l15) * 136 + kk2 * 32 + quad * 8]);
#pragma unroll
            for (int mt2 = 0; mt2 < 4; mt2++)
#pragma unroll
                for (int nt = 0; nt < 2; nt++)
                    accO[mt2][nt] = __builtin_amdgcn_mfma_f32_16x16x32_bf16(av[mt2], bp[nt], accO[mt2][nt], 0, 0, 0);
        }
        __builtin_amdgcn_s_setprio(0);

        __syncthreads();  // all waves done reading Ks/Vs
        if (more) {
#pragma unroll
            for (int p = 0; p < 4; p++) {
                int idx = p * 256 + t;
                int rk = idx >> 3, ck = (idx & 7) * 8;
                int rv = idx >> 4, cv = (idx & 15) * 8;
                short8 kv = (p == 0) ? kpr0 : (p == 1) ? kpr1 : (p == 2) ? kpr2 : kpr3;
                short8 vv = (p == 0) ? vpr0 : (p == 1) ? vpr1 : (p == 2) ? vpr2 : vpr3;
                *(short8*)(&Ks[rk * 72 + ck]) = kv;
                *(short8*)(&Vs[rv * 136 + cv]) = vv;
            }
        }
        __syncthreads();  // next tile ready
    }

    int b = bh >> 4, h = bh & 15;
#pragma unroll
    for (int nt = 0; nt < 2; nt++) {
        float rl = 1.f / lrow[nt];
        int s = qb + wq + nt * 16 + l15;
#pragma unroll
        for (int mt2 = 0; mt2 < 4; mt2++) {
            uint32x2 pk;
            pk.x = cvt_pk_bf16(accO[mt2][nt][0] * rl, accO[mt2][nt][1] * rl);
            pk.y = cvt_pk_bf16(accO[mt2][nt][2] * rl, accO[mt2][nt][3] * rl);
            *(uint32x2*)(&Yatt[((size_t)(b * NS + s)) * ND + h * NHD + mt2 * 16 + quad * 4]) = pk;
        }
    }
}

extern "C" void kernel_launch(void* const* d_in, const int* in_sizes, int n_in,
                              void* d_out, int out_size, void* d_ws, size_t ws_size,
                              hipStream_t stream) {
    // dict order (contractual): consulta, chave, valor, Wq, bq, Wk, bk, Wv, bv, Wo, bo
    const float* consulta = (const float*)d_in[0];
    const float* chave    = (const float*)d_in[1];
    const float* valor    = (const float*)d_in[2];
    const float* Wq = (const float*)d_in[3];
    const float* bq = (const float*)d_in[4];
    const float* Wk = (const float*)d_in[5];
    const float* bk = (const float*)d_in[6];
    const float* Wv = (const float*)d_in[7];
    const float* bv = (const float*)d_in[8];
    const float* Wo = (const float*)d_in[9];
    const float* bo = (const float*)d_in[10];

    const size_t NX = (size_t)8192 * 1024;

    float* cosT = (float*)d_ws;
    float* sinT = cosT + (size_t)NS * 32;
    unsigned short* Qrb = (unsigned short*)(sinT + (size_t)NS * 32);
    unsigned short* Krb = Qrb + NX;
    unsigned short* Vtb = Krb + NX;
    unsigned short* Yat = Vtb + NX;
    unsigned short* Abf = Yat + NX;            // bf16 activation staging (reused)
    unsigned short* Wbf = Abf + NX;            // bf16 weight staging (reused)

    rope_table_kernel<<<NS * 32 / 256, 256, 0, stream>>>(cosT, sinT);

    const int ACT8 = (int)(NX / 8);   // 1048576 vec8 chunks
    const int W8 = ND * ND / 8;       // 131072

    dim3 ggrid(8, 64);

    cast_bf16_kernel<<<ACT8 / 256, 256, 0, stream>>>(consulta, Abf, ACT8);
    cast_bf16_kernel<<<W8 / 256, 256, 0, stream>>>(Wq, Wbf, W8);
    gemm_kernel<1><<<ggrid, 256, 0, stream>>>(Abf, Wbf, bq, Qrb, cosT, sinT, QSCALE);

    cast_bf16_kernel<<<ACT8 / 256, 256, 0, stream>>>(chave, Abf, ACT8);
    cast_bf16_kernel<<<W8 / 256, 256, 0, stream>>>(Wk, Wbf, W8);
    gemm_kernel<1><<<ggrid, 256, 0, stream>>>(Abf, Wbf, bk, Krb, cosT, sinT, 1.0f);

    cast_bf16_kernel<<<ACT8 / 256, 256, 0, stream>>>(valor, Abf, ACT8);
    cast_bf16_kernel<<<W8 / 256, 256, 0, stream>>>(Wv, Wbf, W8);
    gemm_kernel<2><<<ggrid, 256, 0, stream>>>(Abf, Wbf, bv, Vtb, cosT, sinT, 1.0f);

    flash_kernel<<<dim3(32, 32), 256, 0, stream>>>(Qrb, Krb, Vtb, Yat);

    // d_out is FLOAT32 (reference output dtype)
    cast_bf16_kernel<<<W8 / 256, 256, 0, stream>>>(Wo, Wbf, W8);
    gemm_kernel<0><<<ggrid, 256, 0, stream>>>(Yat, Wbf, bo, d_out, cosT, sinT, 1.0f);
}

// Round 5
// 518.434 us; speedup vs baseline: 1.5343x; 1.0804x over previous
//
#include <hip/hip_runtime.h>
#include <hip/hip_bf16.h>

typedef __attribute__((ext_vector_type(8))) short short8;
typedef __attribute__((ext_vector_type(4))) float f32x4;
typedef __attribute__((ext_vector_type(16))) float f32x16;
typedef __attribute__((ext_vector_type(4))) unsigned short ushort4v;
typedef __attribute__((ext_vector_type(4))) float float4v;
typedef __attribute__((ext_vector_type(2))) unsigned int uint32x2;
typedef __attribute__((ext_vector_type(4))) unsigned int uint32x4;

#define NB 2
#define NS 4096
#define ND 1024
#define NH 16
#define NHD 64

// 0.125 * log2(e): folds the 1/sqrt(64) score scale AND the exp->exp2
// conversion into the Q projection (exact up to one fp32 rounding).
#define QSCALE 0.18033688011112042f

__device__ __forceinline__ unsigned short f2bf(float x) {
    union { float f; unsigned u; } v; v.f = x;
    unsigned r = v.u + 0x7FFFu + ((v.u >> 16) & 1u);
    return (unsigned short)(r >> 16);
}

// pack 2 f32 -> u32 of 2 bf16 (RNE), dst[15:0]=lo
__device__ __forceinline__ unsigned cvt_pk_bf16(float lo, float hi) {
    unsigned r;
    asm("v_cvt_pk_bf16_f32 %0, %1, %2" : "=v"(r) : "v"(lo), "v"(hi));
    return r;
}

// async global->LDS, 16B per lane. LDS dest = wave-uniform base + lane*16.
__device__ __forceinline__ void gload_lds16(const unsigned short* g, unsigned short* l) {
    __builtin_amdgcn_global_load_lds(
        (const __attribute__((address_space(1))) void*)g,
        (__attribute__((address_space(3))) void*)l,
        16, 0, 0);
}

__global__ void rope_table_kernel(float* __restrict__ cosT, float* __restrict__ sinT) {
    int i = blockIdx.x * blockDim.x + threadIdx.x;  // [0, NS*32)
    int p = i & 31, s = i >> 5;
    float theta = exp2f(-(float)(2 * p) * (13.287712379549449f / 64.0f));  // 10000^(-2p/64)
    float ang = (float)s * theta;
    float sv, cv;
    sincosf(ang, &sv, &cv);
    cosT[i] = cv; sinT[i] = sv;
}

// fp32 -> bf16 elementwise cast, 8 elems/thread (32B read, 16B write).
__global__ void cast_bf16_kernel(const float* __restrict__ in, unsigned short* __restrict__ out, int n8) {
    int i = blockIdx.x * blockDim.x + threadIdx.x;
    if (i >= n8) return;
    float4v a0 = *(const float4v*)(&in[(size_t)i * 8]);
    float4v a1 = *(const float4v*)(&in[(size_t)i * 8 + 4]);
    short8 s8;
    s8[0] = (short)f2bf(a0.x); s8[1] = (short)f2bf(a0.y);
    s8[2] = (short)f2bf(a0.z); s8[3] = (short)f2bf(a0.w);
    s8[4] = (short)f2bf(a1.x); s8[5] = (short)f2bf(a1.y);
    s8[6] = (short)f2bf(a1.z); s8[7] = (short)f2bf(a1.w);
    *(short8*)(&out[(size_t)i * 8]) = s8;
}

// C = A @ W^T + bias. A: [8192][1024] bf16. W: [1024][1024] bf16 row-major.
// m97 structure: 128x128 tile, BK=32, linear LDS (NO padding - required by
// global_load_lds), width-16 global_load_lds staging, ds_read_b128 fragments.
// EPI 0: plain -> out float32 row-major [8192][1024]  (d_out is fp32!)
// EPI 1: RoPE  -> out [B,H,S,HD] bf16, scaled by oscale (Q pre-scaling)
// EPI 2: V^T   -> out [B,H,HD,S] bf16
template<int EPI>
__global__ __launch_bounds__(256, 2) void gemm_kernel(
    const unsigned short* __restrict__ A,
    const unsigned short* __restrict__ Wb,
    const float* __restrict__ bias,
    void* __restrict__ outv,
    const float* __restrict__ cosT,
    const float* __restrict__ sinT,
    float oscale)
{
    __shared__ unsigned short As[128 * 32];  // linear: row stride 32 (64B)
    __shared__ unsigned short Bs[128 * 32];
    const int t = threadIdx.x;
    const int wave = t >> 6, lane = t & 63;
    const int quad = lane >> 4, l15 = lane & 15;
    const int wm = (wave & 1) * 64, wn = (wave >> 1) * 64;
    const int m0 = blockIdx.y * 128, n0 = blockIdx.x * 128;

    f32x4 acc[4][4];
#pragma unroll
    for (int i = 0; i < 4; i++)
#pragma unroll
        for (int j = 0; j < 4; j++)
            acc[i][j] = f32x4{0.f, 0.f, 0.f, 0.f};

    for (int k0 = 0; k0 < ND; k0 += 32) {
#pragma unroll
        for (int p = 0; p < 2; p++) {
            int idx = p * 256 + t;
            int r = idx >> 2, c = (idx & 3) * 8;
            unsigned short* ldsA = &As[(size_t)(p * 256 + wave * 64) * 8];
            unsigned short* ldsB = &Bs[(size_t)(p * 256 + wave * 64) * 8];
            gload_lds16(&A[(size_t)(m0 + r) * ND + k0 + c], ldsA);
            gload_lds16(&Wb[(size_t)(n0 + r) * ND + k0 + c], ldsB);
        }
        __syncthreads();  // compiler emits vmcnt(0) drain here

        short8 af[4], bfr[4];
#pragma unroll
        for (int mt = 0; mt < 4; mt++)
            af[mt] = *(const short8*)(&As[(wm + mt * 16 + l15) * 32 + quad * 8]);
#pragma unroll
        for (int nt = 0; nt < 4; nt++)
            bfr[nt] = *(const short8*)(&Bs[(wn + nt * 16 + l15) * 32 + quad * 8]);
#pragma unroll
        for (int mt = 0; mt < 4; mt++)
#pragma unroll
            for (int nt = 0; nt < 4; nt++) {
                if (EPI == 0)
                    acc[mt][nt] = __builtin_amdgcn_mfma_f32_16x16x32_bf16(bfr[nt], af[mt], acc[mt][nt], 0, 0, 0);
                else
                    acc[mt][nt] = __builtin_amdgcn_mfma_f32_16x16x32_bf16(af[mt], bfr[nt], acc[mt][nt], 0, 0, 0);
            }
        __syncthreads();
    }

    if (EPI == 0) {
        // operands swapped: D[m=W-row -> quad*4+r][n=seq -> l15]; fp32 output
        float* out = (float*)outv;
#pragma unroll
        for (int mt = 0; mt < 4; mt++) {
            int gm = m0 + wm + mt * 16 + l15;  // seq row
#pragma unroll
            for (int nt = 0; nt < 4; nt++) {
                int gn0 = n0 + wn + nt * 16 + quad * 4;  // feature
                float4v fv;
#pragma unroll
                for (int r = 0; r < 4; r++)
                    fv[r] = acc[mt][nt][r] + bias[gn0 + r];
                *(float4v*)(&out[(size_t)gm * ND + gn0]) = fv;
            }
        }
    } else if (EPI == 1) {
        // D[m=seq -> quad*4+r][n=feature -> l15]
        unsigned short* out = (unsigned short*)outv;
#pragma unroll
        for (int nt = 0; nt < 4; nt++) {
            int gn = n0 + wn + nt * 16 + l15;
            int h = gn >> 6, hd = gn & 63, pr = hd >> 1, im = gn & 1;
            float bv = bias[gn];
#pragma unroll
            for (int mt = 0; mt < 4; mt++) {
                int gm0 = m0 + wm + mt * 16 + quad * 4;
#pragma unroll
                for (int r = 0; r < 4; r++) {
                    int gm = gm0 + r;
                    int b = gm >> 12, s = gm & 4095;
                    float v = acc[mt][nt][r] + bv;
                    float pv = __shfl_xor(v, 1, 64);  // partner feature gn^1, same seq
                    float cv = cosT[s * 32 + pr], sv = sinT[s * 32 + pr];
                    float o = im ? (pv * sv + v * cv) : (v * cv - pv * sv);
                    out[((size_t)(b * NH + h) * NS + s) * NHD + hd] = f2bf(o * oscale);
                }
            }
        }
    } else {
        // V^T: out[((b*H+h)*HD+hd)*S + s]
        unsigned short* out = (unsigned short*)outv;
#pragma unroll
        for (int nt = 0; nt < 4; nt++) {
            int gn = n0 + wn + nt * 16 + l15;
            int h = gn >> 6, hd = gn & 63;
            float bv = bias[gn];
#pragma unroll
            for (int mt = 0; mt < 4; mt++) {
                int gm0 = m0 + wm + mt * 16 + quad * 4;
                int b = gm0 >> 12, s0 = gm0 & 4095;
                ushort4v pk;
#pragma unroll
                for (int r = 0; r < 4; r++)
                    pk[r] = f2bf(acc[mt][nt][r] + bv);
                *(ushort4v*)(&out[((size_t)(b * NH + h) * NHD + hd) * NS + s0]) = pk;
            }
        }
    }
}

// Flash attention, 32x32-MFMA in-register-P structure (m214-v22 style).
// Qr: [BH][S][64] bf16, RoPE'd AND pre-scaled by 0.125*log2e. Kr: same, unscaled.
// Vt: [BH][64][S] bf16. Yatt: [B*S][1024] bf16.
// Block: 128 q-rows of one (b,h); wave owns 32 q-rows. Per 128-key tile:
//   S^T = K.Q^T via mfma_32x32x16 (A=K rows, B=Q rows). D: col(lane&31)=q,
//   row=(reg&3)+8*(reg>>2)+4*(lane>>5)=key. Each lane: ONE q, 64 of 128 keys;
//   partner lane^32 has the rest -> softmax = in-lane tree + ONE xor32 shfl.
//   P -> bf16 via cvt_pk (key-consecutive quartets), then ONE
//   v_permlane32_swap_b32 per register pair assembles PV B-frags in-register.
//   NO P LDS round-trip. LDS = Ks+Vs only (35840 B -> 4 blocks/CU by LDS).
__global__ __launch_bounds__(256, 2) void flash_kernel(
    const unsigned short* __restrict__ Qr,
    const unsigned short* __restrict__ Kr,
    const unsigned short* __restrict__ Vt,
    unsigned short* __restrict__ Yatt)
{
    __shared__ unsigned short Ks[128 * 72];    // pad 64->72 (16B-aligned rows)
    __shared__ unsigned short Vs[64 * 136];    // pad 128->136
    const int t = threadIdx.x;
    const int wave = t >> 6, lane = t & 63;
    const int l31 = lane & 31, h = lane >> 5;
    const int bh = blockIdx.y;
    const int qb = blockIdx.x * 128;
    const int wq = wave * 32;
    const size_t base = (size_t)bh * NS * NHD;

    // Q B-frags: row q = qb+wq+l31, k(d) = ks*16 + h*8 + e
    short8 qf[4];
#pragma unroll
    for (int ks = 0; ks < 4; ks++)
        qf[ks] = *(const short8*)(&Qr[base + (size_t)(qb + wq + l31) * NHD + ks * 16 + h * 8]);

    f32x16 accO[2];
#pragma unroll
    for (int dt = 0; dt < 2; dt++)
#pragma unroll
        for (int r = 0; r < 16; r++)
            accO[dt][r] = 0.f;
    float mrow = -1e30f, lrow = 0.f;

    for (int j0 = 0; j0 < NS; j0 += 128) {
        // stage K/V tile
#pragma unroll
        for (int p = 0; p < 4; p++) {
            int idx = p * 256 + t;
            { int r = idx >> 3, c = (idx & 7) * 8;
              *(short8*)(&Ks[r * 72 + c]) = *(const short8*)(&Kr[base + (size_t)(j0 + r) * NHD + c]); }
            { int r = idx >> 4, c = (idx & 15) * 8;
              *(short8*)(&Vs[r * 136 + c]) = *(const short8*)(&Vt[(size_t)(bh * NHD + r) * NS + j0 + c]); }
        }
        __syncthreads();

        // S^T = K . Q^T (exp2 domain; Q pre-scaled)
        f32x16 sa[4];
#pragma unroll
        for (int kt = 0; kt < 4; kt++)
#pragma unroll
            for (int r = 0; r < 16; r++)
                sa[kt][r] = 0.f;
        __builtin_amdgcn_s_setprio(1);
#pragma unroll
        for (int kt = 0; kt < 4; kt++)
#pragma unroll
            for (int ks = 0; ks < 4; ks++) {
                short8 ak = *(const short8*)(&Ks[(kt * 32 + l31) * 72 + ks * 16 + h * 8]);
                sa[kt] = __builtin_amdgcn_mfma_f32_32x32x16_bf16(ak, qf[ks], sa[kt], 0, 0, 0);
            }
        __builtin_amdgcn_s_setprio(0);

        // --- softmax: each lane owns one q (l31), 64 of 128 keys ---
        float mx = -1e30f;
#pragma unroll
        for (int kt = 0; kt < 4; kt++) {
            float m0v = fmaxf(fmaxf(sa[kt][0], sa[kt][1]), fmaxf(sa[kt][2], sa[kt][3]));
            float m1v = fmaxf(fmaxf(sa[kt][4], sa[kt][5]), fmaxf(sa[kt][6], sa[kt][7]));
            float m2v = fmaxf(fmaxf(sa[kt][8], sa[kt][9]), fmaxf(sa[kt][10], sa[kt][11]));
            float m3v = fmaxf(fmaxf(sa[kt][12], sa[kt][13]), fmaxf(sa[kt][14], sa[kt][15]));
            mx = fmaxf(mx, fmaxf(fmaxf(m0v, m1v), fmaxf(m2v, m3v)));
        }
        mx = fmaxf(mx, __shfl_xor(mx, 32, 64));
        // T13 defer-max: rescale only when tile max exceeds running max by >8
        if (!__all(mx <= mrow + 8.0f)) {
            float mnew = fmaxf(mrow, mx);
            float alpha = exp2f(mrow - mnew);
            lrow *= alpha;
#pragma unroll
            for (int dt = 0; dt < 2; dt++)
#pragma unroll
                for (int r = 0; r < 16; r++)
                    accO[dt][r] *= alpha;
            mrow = mnew;
        }
        float ls0 = 0.f, ls1 = 0.f, ls2 = 0.f, ls3 = 0.f;
        unsigned pk[4][4][2];  // [key-tile][quartet g][pair j]
#pragma unroll
        for (int kt = 0; kt < 4; kt++)
#pragma unroll
            for (int g = 0; g < 4; g++) {
                float p0 = exp2f(sa[kt][4 * g + 0] - mrow);
                float p1 = exp2f(sa[kt][4 * g + 1] - mrow);
                float p2 = exp2f(sa[kt][4 * g + 2] - mrow);
                float p3 = exp2f(sa[kt][4 * g + 3] - mrow);
                ls0 += p0; ls1 += p1; ls2 += p2; ls3 += p3;
                pk[kt][g][0] = cvt_pk_bf16(p0, p1);
                pk[kt][g][1] = cvt_pk_bf16(p2, p3);
            }
        float lsum = (ls0 + ls1) + (ls2 + ls3);
        lsum += __shfl_xor(lsum, 32, 64);
        lrow += lsum;

        // in-register P redistribution: swap vdst_hi <-> vsrc_lo.
        // After swap(pk[t][2u][j], pk[t][2u+1][j]):
        //   pk[t][2u][j]   = quartetA (keys 32t+16u+8h + 2j+{0,1})
        //   pk[t][2u+1][j] = quartetB (keys 32t+16u+8h+4 + 2j+{0,1})
#pragma unroll
        for (int t2 = 0; t2 < 4; t2++)
#pragma unroll
            for (int u = 0; u < 2; u++)
#pragma unroll
                for (int j = 0; j < 2; j++)
                    asm volatile("v_permlane32_swap_b32 %0, %1"
                                 : "+v"(pk[t2][2 * u][j]), "+v"(pk[t2][2 * u + 1][j]));

        // PV: O^T[d][q] += V^T . P^T, B-frag assembled from swapped pk
        __builtin_amdgcn_s_setprio(1);
#pragma unroll
        for (int ks2 = 0; ks2 < 8; ks2++) {
            const int t2 = ks2 >> 1, u = ks2 & 1;
            uint32x4 bw;
            bw.x = pk[t2][2 * u][0];     bw.y = pk[t2][2 * u][1];
            bw.z = pk[t2][2 * u + 1][0]; bw.w = pk[t2][2 * u + 1][1];
            short8 bp = __builtin_bit_cast(short8, bw);
#pragma unroll
            for (int dt = 0; dt < 2; dt++) {
                short8 av = *(const short8*)(&Vs[(dt * 32 + l31) * 136 + ks2 * 16 + h * 8]);
                accO[dt] = __builtin_amdgcn_mfma_f32_32x32x16_bf16(av, bp, accO[dt], 0, 0, 0);
            }
        }
        __builtin_amdgcn_s_setprio(0);
        __syncthreads();
    }

    // epilogue: lane owns q = l31; accO row = 8g + 4h + (reg&3) within dt*32
    int b = bh >> 4, hh = bh & 15;
    float rl = 1.f / lrow;
    int s = qb + wq + l31;
#pragma unroll
    for (int dt = 0; dt < 2; dt++)
#pragma unroll
        for (int g = 0; g < 4; g++) {
            uint32x2 w;
            w.x = cvt_pk_bf16(accO[dt][4 * g + 0] * rl, accO[dt][4 * g + 1] * rl);
            w.y = cvt_pk_bf16(accO[dt][4 * g + 2] * rl, accO[dt][4 * g + 3] * rl);
            int d0 = dt * 32 + 8 * g + 4 * h;
            *(uint32x2*)(&Yatt[((size_t)(b * NS + s)) * ND + hh * NHD + d0]) = w;
        }
}

extern "C" void kernel_launch(void* const* d_in, const int* in_sizes, int n_in,
                              void* d_out, int out_size, void* d_ws, size_t ws_size,
                              hipStream_t stream) {
    // dict order (contractual): consulta, chave, valor, Wq, bq, Wk, bk, Wv, bv, Wo, bo
    const float* consulta = (const float*)d_in[0];
    const float* chave    = (const float*)d_in[1];
    const float* valor    = (const float*)d_in[2];
    const float* Wq = (const float*)d_in[3];
    const float* bq = (const float*)d_in[4];
    const float* Wk = (const float*)d_in[5];
    const float* bk = (const float*)d_in[6];
    const float* Wv = (const float*)d_in[7];
    const float* bv = (const float*)d_in[8];
    const float* Wo = (const float*)d_in[9];
    const float* bo = (const float*)d_in[10];

    const size_t NX = (size_t)8192 * 1024;

    float* cosT = (float*)d_ws;
    float* sinT = cosT + (size_t)NS * 32;
    unsigned short* Qrb = (unsigned short*)(sinT + (size_t)NS * 32);
    unsigned short* Krb = Qrb + NX;
    unsigned short* Vtb = Krb + NX;
    unsigned short* Yat = Vtb + NX;
    unsigned short* Abf = Yat + NX;            // bf16 activation staging (reused)
    unsigned short* Wbf = Abf + NX;            // bf16 weight staging (reused)

    rope_table_kernel<<<NS * 32 / 256, 256, 0, stream>>>(cosT, sinT);

    const int ACT8 = (int)(NX / 8);   // 1048576 vec8 chunks
    const int W8 = ND * ND / 8;       // 131072

    dim3 ggrid(8, 64);

    cast_bf16_kernel<<<ACT8 / 256, 256, 0, stream>>>(consulta, Abf, ACT8);
    cast_bf16_kernel<<<W8 / 256, 256, 0, stream>>>(Wq, Wbf, W8);
    gemm_kernel<1><<<ggrid, 256, 0, stream>>>(Abf, Wbf, bq, Qrb, cosT, sinT, QSCALE);

    cast_bf16_kernel<<<ACT8 / 256, 256, 0, stream>>>(chave, Abf, ACT8);
    cast_bf16_kernel<<<W8 / 256, 256, 0, stream>>>(Wk, Wbf, W8);
    gemm_kernel<1><<<ggrid, 256, 0, stream>>>(Abf, Wbf, bk, Krb, cosT, sinT, 1.0f);

    cast_bf16_kernel<<<ACT8 / 256, 256, 0, stream>>>(valor, Abf, ACT8);
    cast_bf16_kernel<<<W8 / 256, 256, 0, stream>>>(Wv, Wbf, W8);
    gemm_kernel<2><<<ggrid, 256, 0, stream>>>(Abf, Wbf, bv, Vtb, cosT, sinT, 1.0f);

    flash_kernel<<<dim3(32, 32), 256, 0, stream>>>(Qrb, Krb, Vtb, Yat);

    // d_out is FLOAT32 (reference output dtype)
    cast_bf16_kernel<<<W8 / 256, 256, 0, stream>>>(Wo, Wbf, W8);
    gemm_kernel<0><<<ggrid, 256, 0, stream>>>(Yat, Wbf, bo, d_out, cosT, sinT, 1.0f);
}